// Round 10
// baseline (192.883 us; speedup 1.0000x reference)
//
#include <hip/hip_runtime.h>
#include <math.h>
#include <stdint.h>

#define SEQ  2048
#define LOG2E 1.4426950408889634f

typedef __attribute__((ext_vector_type(4))) float f32x4;
typedef __attribute__((ext_vector_type(16))) float f32x16;
typedef __attribute__((ext_vector_type(8))) short bf16x8;

template <int V> struct IC { static constexpr int value = V; };

// pack two fp32 -> bf16x2 dword via v_perm (round-half-up; ties-only diff vs RNE)
__device__ __forceinline__ unsigned packbf(float a, float b) {
    return __builtin_amdgcn_perm(__float_as_uint(b) + 0x8000u,
                                 __float_as_uint(a) + 0x8000u, 0x07060302u);
}

// ---------------------------------------------------------------------------
// QKV GEMM with FUSED fp32->bf16 convert. C = x(M,512) @ W(N,512)^T + bias,
// N=1536 (Q|K|V), grid (12,64), 128x128 tiles, BK=32.
// LDS DOUBLE-buffered, ONE barrier per K-step (writes to buf^1 overlap MFMA
// reads of buf; global loads for ki+1 issue right after the barrier).
// Frag-linear outputs (exact MFMA fragment image; attn reads straight from L2):
//   Q'/K': [bh][q32tile(64)][kt(4)][lane(64)][8]   (TR orientation; Q *LOG2E)
//   V'   : [bh][j64tile(32)][dg*4+p(8)][lane(64)][8]
// ---------------------------------------------------------------------------
__global__ __launch_bounds__(256, 3) void qkv_kernel(
    const float* __restrict__ xf, const float* __restrict__ wqf,
    const float* __restrict__ wkf, const float* __restrict__ wvf,
    const float* __restrict__ bq, const float* __restrict__ bk,
    const float* __restrict__ bv,
    unsigned short* __restrict__ Qw, unsigned short* __restrict__ Kw,
    unsigned short* __restrict__ VTw)
{
    __shared__ __align__(16) unsigned short smem[16384]; // As[2]4096 | Bs[2]4096
    unsigned short* As = smem;
    unsigned short* Bs = smem + 8192;

    const int t = threadIdx.x;
    const int w = t >> 6, lane = t & 63, quad = (t >> 4) & 3, l15 = t & 15;
    const int wr = w >> 1, wc = w & 1;
    const int m0 = blockIdx.y * 128;
    const int n0 = blockIdx.x * 128;
    const int which = n0 >> 9;                 // 0=Q 1=K 2=V
    const float* wbase = which == 0 ? wqf : (which == 1 ? wkf : wvf);
    const int nrow = n0 & 511;

    const int ar = t >> 2, akq = t & 3;
    const float* ax = xf + (size_t)(m0 + ar) * 512 + akq * 8;
    const float* bx = wbase + (size_t)(nrow + ar) * 512 + akq * 8;
    const int lws = (ar & 15) | (akq << 4);
    const int off0 = (ar >> 4) * 512 + lws * 8;
    const int off1 = off0 + 4 * 512;

    f32x4 acc[4][4];
#pragma unroll
    for (int mt = 0; mt < 4; ++mt)
#pragma unroll
        for (int nt = 0; nt < 4; ++nt) acc[mt][nt] = (f32x4){0.f, 0.f, 0.f, 0.f};

    float4 ra[4], rb[4];
    auto loadt = [&](int k0) {
        ra[0] = *(const float4*)(ax + k0);
        ra[1] = *(const float4*)(ax + k0 + 4);
        ra[2] = *(const float4*)(ax + 32768 + k0);
        ra[3] = *(const float4*)(ax + 32768 + k0 + 4);
        rb[0] = *(const float4*)(bx + k0);
        rb[1] = *(const float4*)(bx + k0 + 4);
        rb[2] = *(const float4*)(bx + 32768 + k0);
        rb[3] = *(const float4*)(bx + 32768 + k0 + 4);
    };
    auto writet = [&](int buf) {
        const int bo = buf * 4096;
        uint4 p;
        p.x = packbf(ra[0].x, ra[0].y); p.y = packbf(ra[0].z, ra[0].w);
        p.z = packbf(ra[1].x, ra[1].y); p.w = packbf(ra[1].z, ra[1].w);
        *(uint4*)(As + bo + off0) = p;
        p.x = packbf(ra[2].x, ra[2].y); p.y = packbf(ra[2].z, ra[2].w);
        p.z = packbf(ra[3].x, ra[3].y); p.w = packbf(ra[3].z, ra[3].w);
        *(uint4*)(As + bo + off1) = p;
        p.x = packbf(rb[0].x, rb[0].y); p.y = packbf(rb[0].z, rb[0].w);
        p.z = packbf(rb[1].x, rb[1].y); p.w = packbf(rb[1].z, rb[1].w);
        *(uint4*)(Bs + bo + off0) = p;
        p.x = packbf(rb[2].x, rb[2].y); p.y = packbf(rb[2].z, rb[2].w);
        p.z = packbf(rb[3].x, rb[3].y); p.w = packbf(rb[3].z, rb[3].w);
        *(uint4*)(Bs + bo + off1) = p;
    };

    loadt(0);
    writet(0);
    auto kloop = [&](auto TRC) {
        constexpr int TR = decltype(TRC)::value;
        for (int ki = 0; ki < 16; ++ki) {
            __syncthreads();
            if (ki < 15) loadt((ki + 1) * 32);
            const int bo = (ki & 1) * 4096;
            bf16x8 af[4], bfr[4];
#pragma unroll
            for (int mt = 0; mt < 4; ++mt)
                af[mt] = *(const bf16x8*)(As + bo + ((wr * 4 + mt) * 64 + lane) * 8);
#pragma unroll
            for (int nt = 0; nt < 4; ++nt)
                bfr[nt] = *(const bf16x8*)(Bs + bo + ((wc * 4 + nt) * 64 + lane) * 8);
#pragma unroll
            for (int mt = 0; mt < 4; ++mt)
#pragma unroll
                for (int nt = 0; nt < 4; ++nt) {
                    if (TR)
                        acc[mt][nt] = __builtin_amdgcn_mfma_f32_16x16x32_bf16(
                            bfr[nt], af[mt], acc[mt][nt], 0, 0, 0);
                    else
                        acc[mt][nt] = __builtin_amdgcn_mfma_f32_16x16x32_bf16(
                            af[mt], bfr[nt], acc[mt][nt], 0, 0, 0);
                }
            if (ki < 15) writet((ki + 1) & 1);
        }
    };
    if (which < 2) kloop(IC<1>{});
    else           kloop(IC<0>{});

    if (which == 2) {
        // V: normal orientation -> frag-linear V'
#pragma unroll
        for (int nt = 0; nt < 4; ++nt) {
            const int n = n0 + wc * 64 + nt * 16 + l15;
            const float bias = bv[n & 511];
            const int h = (n >> 6) & 7, d = n & 63;
#pragma unroll
            for (int mt = 0; mt < 4; ++mt) {
                const int mb = m0 + wr * 64 + mt * 16 + quad * 4;
                const int bi = mb >> 11, ns = mb & 2047;
                const int bhl = bi * 8 + h;
                const f32x4 v = acc[mt][nt];
                uint2 pk;
                pk.x = packbf(v[0] + bias, v[1] + bias);
                pk.y = packbf(v[2] + bias, v[3] + bias);
                const size_t off =
                    ((size_t)(bhl * 32 + (ns >> 6)) * 8 + ((d >> 5) << 2) +
                     ((ns >> 4) & 3)) * 512 +
                    ((d & 31) << 3) + ((ns & 8) << 5) + (ns & 7);
                *(uint2*)(VTw + off) = pk;
            }
        }
    } else {
        // Q/K: TR orientation -> frag-linear Q'/K'
        const float sc = which ? 1.f : LOG2E;
        const float* bpt = which ? bk : bq;
        unsigned short* base = which ? Kw : Qw;
#pragma unroll
        for (int nt = 0; nt < 4; ++nt) {
            const int nb = n0 + wc * 64 + nt * 16 + quad * 4;   // d base
            const f32x4 bvv = *(const f32x4*)(bpt + (nb & 511));
            const int h = (nb >> 6) & 7, d0 = nb & 63;
#pragma unroll
            for (int mt = 0; mt < 4; ++mt) {
                const int nsg = m0 + wr * 64 + mt * 16 + l15;   // ns (col=l15)
                const int bi = nsg >> 11, ns = nsg & 2047;
                const int bhl = bi * 8 + h;
                const f32x4 v = acc[mt][nt];
                uint2 pk;
                pk.x = packbf((v[0] + bvv[0]) * sc, (v[1] + bvv[1]) * sc);
                pk.y = packbf((v[2] + bvv[2]) * sc, (v[3] + bvv[3]) * sc);
                const size_t off =
                    ((size_t)(bhl * 64 + (ns >> 5)) * 4 + (d0 >> 4)) * 512 +
                    ((d0 & 8) << 5) + ((ns & 31) << 3) + (d0 & 7);
                *(uint2*)(base + off) = pk;
            }
        }
    }
}

// ---------------------------------------------------------------------------
// Out-projection GEMM: out = Owb(M,512) @ Wp(512,512)^T + bp, fp32 out.
// 128x64 tiles, grid (8,64); Wp converted inline. LDS double-buffered,
// ONE barrier per K-step.
// ---------------------------------------------------------------------------
__global__ __launch_bounds__(256, 3) void outproj_kernel(
    const unsigned short* __restrict__ Aw, const float* __restrict__ wpf,
    const float* __restrict__ bp, float* __restrict__ out)
{
    __shared__ __align__(16) unsigned short smem[12288]; // As[2]4096 | Bs[2]2048
    unsigned short* As = smem;
    unsigned short* Bs = smem + 8192;

    const int t = threadIdx.x;
    const int w = t >> 6, lane = t & 63, quad = (t >> 4) & 3, l15 = t & 15;
    const int wr = w >> 1, wc = w & 1;
    const int m0 = blockIdx.y * 128;
    const int n0 = blockIdx.x * 64;

    const int ar = t >> 2, akq = t & 3;
    const unsigned short* ap = Aw + (size_t)(m0 + ar) * 512 + akq * 8;
    const float* bx = wpf + (size_t)(n0 + ar) * 512 + akq * 8;
    const int lws = (ar & 15) | (akq << 4);
    const int off0 = (ar >> 4) * 512 + lws * 8;
    const int off1 = off0 + 4 * 512;
    const int boff = (ar >> 4) * 512 + lws * 8;

    f32x4 acc[4][2];
#pragma unroll
    for (int mt = 0; mt < 4; ++mt)
#pragma unroll
        for (int nt = 0; nt < 2; ++nt) acc[mt][nt] = (f32x4){0.f, 0.f, 0.f, 0.f};

    uint4 ra0, ra1;
    float4 rb0, rb1;
    auto loadt = [&](int k0) {
        ra0 = *(const uint4*)(ap + k0);
        ra1 = *(const uint4*)(ap + 32768 + k0);
        rb0 = *(const float4*)(bx + k0);
        rb1 = *(const float4*)(bx + k0 + 4);
    };
    auto writet = [&](int buf) {
        *(uint4*)(As + buf * 4096 + off0) = ra0;
        *(uint4*)(As + buf * 4096 + off1) = ra1;
        uint4 p;
        p.x = packbf(rb0.x, rb0.y); p.y = packbf(rb0.z, rb0.w);
        p.z = packbf(rb1.x, rb1.y); p.w = packbf(rb1.z, rb1.w);
        *(uint4*)(Bs + buf * 2048 + boff) = p;
    };

    loadt(0);
    writet(0);
    for (int ki = 0; ki < 16; ++ki) {
        __syncthreads();
        if (ki < 15) loadt((ki + 1) * 32);
        const int ba = (ki & 1) * 4096, bb = (ki & 1) * 2048;
        bf16x8 af[4], bfr[2];
#pragma unroll
        for (int mt = 0; mt < 4; ++mt)
            af[mt] = *(const bf16x8*)(As + ba + ((wr * 4 + mt) * 64 + lane) * 8);
#pragma unroll
        for (int nt = 0; nt < 2; ++nt)
            bfr[nt] = *(const bf16x8*)(Bs + bb + ((wc * 2 + nt) * 64 + lane) * 8);
#pragma unroll
        for (int mt = 0; mt < 4; ++mt)
#pragma unroll
            for (int nt = 0; nt < 2; ++nt)
                acc[mt][nt] = __builtin_amdgcn_mfma_f32_16x16x32_bf16(
                    af[mt], bfr[nt], acc[mt][nt], 0, 0, 0);
        if (ki < 15) writet((ki + 1) & 1);
    }

#pragma unroll
    for (int nt = 0; nt < 2; ++nt) {
        const int n = n0 + wc * 32 + nt * 16 + l15;
        const float bias = bp[n];
#pragma unroll
        for (int mt = 0; mt < 4; ++mt) {
            const int mb = m0 + wr * 64 + mt * 16 + quad * 4;
            const f32x4 v = acc[mt][nt];
#pragma unroll
            for (int r = 0; r < 4; ++r)
                out[(size_t)(mb + r) * 512 + n] = v[r] + bias;
        }
    }
}

// ---------------------------------------------------------------------------
// bf16 32x32x16-MFMA flash attention — zero LDS/barriers in the K-loop,
// SOFTWARE-PIPELINED 2 key-tiles deep: S(jt+1) MFMAs (from K frags loaded one
// iter earlier) issue BEFORE the exp/pack VALU block of jt, so the matrix pipe
// works during the trans-heavy phase. Grid (32,32) = 4 blocks/CU. Block=64 q;
// wave = (qh: 32-q group, jh: 32-key half) — legal: no-max softmax is a pure
// sum. End: LDS merge of (O,l) across jh pair.  att = softmax(unscaled)/sqrt(512)
// ---------------------------------------------------------------------------
__global__ __launch_bounds__(256, 4) void attn_kernel(
    const unsigned short* __restrict__ Qf, const unsigned short* __restrict__ Kf,
    const unsigned short* __restrict__ Vf, unsigned short* __restrict__ Ow)
{
    __shared__ float cb[4224];   // O partials 4096 + l partials 128
    const int t = threadIdx.x;
    const int w = t >> 6, lane = t & 63;
    const int l31 = lane & 31, hlf = lane >> 5;
    const int qh = w >> 1, jh = w & 1;

    const int bh = blockIdx.x;                 // bh%8 pins (b,h) to one XCD
    const int q0 = blockIdx.y * 64;
    const int qg = (q0 >> 5) + qh;             // global 32-q group, 0..63

    const unsigned short* Qp = Qf + ((size_t)(bh * 64 + qg) * 4) * 512 + lane * 8;
    const unsigned short* Kp = Kf + (size_t)bh * 131072 + (jh * 4) * 512 + lane * 8;
    const unsigned short* Vp = Vf + (size_t)bh * 131072 + lane * 8;

    bf16x8 qf[4];
#pragma unroll
    for (int kt = 0; kt < 4; ++kt)
        qf[kt] = *(const bf16x8*)(Qp + kt * 512);

    f32x16 zero;
#pragma unroll
    for (int r = 0; r < 16; ++r) zero[r] = 0.f;

    float lpart = 0.f;
    f32x16 Ot[2];
    Ot[0] = zero; Ot[1] = zero;

    // ---- pipeline prologue: kc <- K(0); st_cur = S(kc); kc <- K(1) ----
    bf16x8 kc[4];
#pragma unroll
    for (int c = 0; c < 4; ++c)
        kc[c] = *(const bf16x8*)(Kp + c * 512);
    f32x16 st_cur = zero;
#pragma unroll
    for (int kt = 0; kt < 4; ++kt)
        st_cur = __builtin_amdgcn_mfma_f32_32x32x16_bf16(kc[kt], qf[kt], st_cur, 0, 0, 0);
#pragma unroll
    for (int c = 0; c < 4; ++c)
        kc[c] = *(const bf16x8*)(Kp + 4096 + c * 512);

#pragma unroll 2
    for (int jt = 0; jt < 32; ++jt) {
        // S(jt+1) from kc — issued FIRST so matrix pipe overlaps the exp block
        f32x16 st_next = zero;
        if (jt < 31) {
#pragma unroll
            for (int kt = 0; kt < 4; ++kt)
                st_next = __builtin_amdgcn_mfma_f32_32x32x16_bf16(
                    kc[kt], qf[kt], st_next, 0, 0, 0);
        }
        // kc <- K(jt+2) (clamped; kc regs free after the MFMAs above)
        {
            const int j2 = (jt < 30) ? jt + 2 : 31;
#pragma unroll
            for (int c = 0; c < 4; ++c)
                kc[c] = *(const bf16x8*)(Kp + (size_t)j2 * 4096 + c * 512);
        }
        // V frags for jt (consumed at PV, ~300 cyc later)
        bf16x8 vc[4];
#pragma unroll
        for (int dg = 0; dg < 2; ++dg)
#pragma unroll
            for (int p = 0; p < 2; ++p)
                vc[dg * 2 + p] = *(const bf16x8*)(
                    Vp + (size_t)jt * 4096 + (dg * 4 + jh * 2 + p) * 512);

        // p = 2^s (no max; logits bounded); tree-summed l
#pragma unroll
        for (int r = 0; r < 16; ++r)
            st_cur[r] = __builtin_amdgcn_exp2f(st_cur[r]);
        {
            float s01 = st_cur[0] + st_cur[1],   s23 = st_cur[2] + st_cur[3];
            float s45 = st_cur[4] + st_cur[5],   s67 = st_cur[6] + st_cur[7];
            float s89 = st_cur[8] + st_cur[9],   sAB = st_cur[10] + st_cur[11];
            float sCD = st_cur[12] + st_cur[13], sEF = st_cur[14] + st_cur[15];
            lpart += ((s01 + s23) + (s45 + s67)) + ((s89 + sAB) + (sCD + sEF));
        }

        // P^T -> B-frags (lane-half exchange only)
        bf16x8 pf[2];
#pragma unroll
        for (int p = 0; p < 2; ++p) {
            const int r0 = p * 8;
            const unsigned a0 = packbf(st_cur[r0 + 0], st_cur[r0 + 1]);
            const unsigned a1 = packbf(st_cur[r0 + 2], st_cur[r0 + 3]);
            const unsigned b0 = packbf(st_cur[r0 + 4], st_cur[r0 + 5]);
            const unsigned b1 = packbf(st_cur[r0 + 6], st_cur[r0 + 7]);
            const unsigned ta0 = (unsigned)__shfl_xor((int)a0, 32);
            const unsigned ta1 = (unsigned)__shfl_xor((int)a1, 32);
            const unsigned tb0 = (unsigned)__shfl_xor((int)b0, 32);
            const unsigned tb1 = (unsigned)__shfl_xor((int)b1, 32);
            union { unsigned u[4]; bf16x8 v; } pb;
            pb.u[0] = hlf ? tb0 : a0;
            pb.u[1] = hlf ? tb1 : a1;
            pb.u[2] = hlf ? b0 : ta0;
            pb.u[3] = hlf ? b1 : ta1;
            pf[p] = pb.v;
        }

        // O^T += V^T . P^T over this key half
#pragma unroll
        for (int dg = 0; dg < 2; ++dg)
#pragma unroll
            for (int p = 0; p < 2; ++p)
                Ot[dg] = __builtin_amdgcn_mfma_f32_32x32x16_bf16(
                    vc[dg * 2 + p], pf[p], Ot[dg], 0, 0, 0);

        st_cur = st_next;
    }

    // ---- merge (O, l) across the jh pair; jh=0 stores ----
    if (jh == 1) {
#pragma unroll
        for (int dg = 0; dg < 2; ++dg)
#pragma unroll
            for (int k = 0; k < 4; ++k) {
                float4 v = make_float4(Ot[dg][k * 4 + 0], Ot[dg][k * 4 + 1],
                                       Ot[dg][k * 4 + 2], Ot[dg][k * 4 + 3]);
                *(float4*)(cb + ((qh * 2 + dg) * 4 + k) * 256 + lane * 4) = v;
            }
        cb[4096 + qh * 64 + lane] = lpart;
    }
    __syncthreads();
    if (jh == 0) {
#pragma unroll
        for (int dg = 0; dg < 2; ++dg)
#pragma unroll
            for (int k = 0; k < 4; ++k) {
                const float4 v =
                    *(const float4*)(cb + ((qh * 2 + dg) * 4 + k) * 256 + lane * 4);
                Ot[dg][k * 4 + 0] += v.x; Ot[dg][k * 4 + 1] += v.y;
                Ot[dg][k * 4 + 2] += v.z; Ot[dg][k * 4 + 3] += v.w;
            }
        float lv = lpart + cb[4096 + qh * 64 + lane];
        lv += __shfl_xor(lv, 32);
        const float inv = 1.0f / (lv * 22.627416997969522f);

        // O^T rows: d = dg*32 + 8*(reg>>2) + (reg&3) + 4*hlf; col q = l31
        const int bi = bh >> 3, h = bh & 7;
        const int ns = q0 + qh * 32 + l31;
        unsigned short* dst = Ow + ((size_t)bi * SEQ + ns) * 512 + h * 64 + hlf * 4;
#pragma unroll
        for (int dg = 0; dg < 2; ++dg)
#pragma unroll
            for (int rb = 0; rb < 4; ++rb) {
                uint2 pk;
                pk.x = packbf(Ot[dg][rb * 4 + 0] * inv, Ot[dg][rb * 4 + 1] * inv);
                pk.y = packbf(Ot[dg][rb * 4 + 2] * inv, Ot[dg][rb * 4 + 3] * inv);
                *(uint2*)(dst + dg * 32 + rb * 8) = pk;
            }
    }
}

// ---------------------------------------------------------------------------
extern "C" void kernel_launch(void* const* d_in, const int* in_sizes, int n_in,
                              void* d_out, int out_size, void* d_ws, size_t ws_size,
                              hipStream_t stream)
{
    const float* x  = (const float*)d_in[0];
    const float* Wq = (const float*)d_in[1];
    const float* bq = (const float*)d_in[2];
    const float* Wk = (const float*)d_in[3];
    const float* bk = (const float*)d_in[4];
    const float* Wv = (const float*)d_in[5];
    const float* bv = (const float*)d_in[6];
    const float* Wp = (const float*)d_in[7];
    const float* bp = (const float*)d_in[8];

    unsigned short* ws = (unsigned short*)d_ws;
    unsigned short* Qw  = ws;                  // Q' frag-linear, *log2e (8 MB)
    unsigned short* Kw  = Qw + 4194304;        // K' frag-linear
    unsigned short* VTw = Kw + 4194304;        // V' frag-linear
    unsigned short* Owb = VTw + 4194304;       // [b][ns][512] bf16

    qkv_kernel<<<dim3(12, 64), 256, 0, stream>>>(
        x, Wq, Wk, Wv, bq, bk, bv, Qw, Kw, VTw);
    attn_kernel<<<dim3(32, 32), 256, 0, stream>>>(Qw, Kw, VTw, Owb);
    outproj_kernel<<<dim3(8, 64), 256, 0, stream>>>(Owb, Wp, bp, (float*)d_out);
}